// Round 4
// baseline (61.240 us; speedup 1.0000x reference)
//
#include <hip/hip_runtime.h>
#include <stdint.h>

#define TILE_LEN 16
#define KMAX 64
#define IMGW 512
#define IMGH 512
#define TXN (IMGW / TILE_LEN)   // 32
#define TYN (IMGH / TILE_LEN)   // 32
#define ROWCAP 4096             // dense per-row capacity (expected ~1500)
#define PREPB 1024
#define SEGCAP PREPB            // per-(block,row) segment cap == block size
#define NBLKMAX 32

// ---------------------------------------------------------------------------
// Kernel 1: per-gaussian prep + deterministic-layout row binning.
// pA = (px, py, radius, opacity); pB = (a, b, c, det); pC = (r, g, b, 0)
// indexed by ORIGINAL gaussian index.
// Each block owns a private segment per row (capacity = block size, so no
// overflow is possible) and writes its per-row count with a plain store --
// no global atomics, no memset needed (everything fully overwritten each
// launch -> graph-replay safe). Order within a segment is nondeterministic;
// sort_rows makes the final order deterministic via unique keys.
// ---------------------------------------------------------------------------
__global__ __launch_bounds__(PREPB) void prep(
    const float* __restrict__ pos2d, const float* __restrict__ cov2d,
    const float* __restrict__ opac,  const float* __restrict__ color,
    float4* __restrict__ pA, float4* __restrict__ pB, float4* __restrict__ pC,
    int* __restrict__ blkcnt, int* __restrict__ bins_seg, int nblk, int N)
{
    __shared__ int lpos[TYN];

    const int t = threadIdx.x;
    const int blk = blockIdx.x;
    if (t < TYN) lpos[t] = 0;
    __syncthreads();

    const int i = blk * PREPB + t;

    float yp = 0.0f, ym = 0.0f;
    int ty0 = 0, ty1 = -1;

    if (i < N) {
        const float a = cov2d[4 * i + 0];
        const float b = cov2d[4 * i + 1];
        const float c = cov2d[4 * i + 3];

        // radius chain with _rn intrinsics: forbids fma contraction
        // (selection-critical, feeds exact bbox-overlap compares)
        const float trace = __fadd_rn(a, c);
        const float det   = __fsub_rn(__fmul_rn(a, c), __fmul_rn(b, b));
        const float tt    = __fmul_rn(trace, trace);
        float arg         = __fsub_rn(tt, __fmul_rn(4.0f, det));
        arg = fmaxf(arg, 0.0f);
        const float t1 = __fmul_rn(0.5f, trace);
        const float t2 = __fmul_rn(0.5f, sqrtf(arg));
        const float lam = fmaxf(__fsub_rn(t1, t2), __fadd_rn(t1, t2));
        const float radius = __fmul_rn(3.0f, sqrtf(lam));

        const float px = pos2d[2 * i];
        const float py = pos2d[2 * i + 1];

        pA[i] = make_float4(px, py, radius, opac[i]);
        pB[i] = make_float4(a, b, c, det);
        pC[i] = make_float4(color[3 * i], color[3 * i + 1], color[3 * i + 2], 0.0f);

        // conservative row range (+/-1 tile margin), exact test per row
        ty0 = max((int)floorf((py - radius) * 0.0625f) - 1, 0);
        ty1 = min((int)floorf((py + radius) * 0.0625f) + 1, TYN - 1);
        yp = __fadd_rn(py, radius);
        ym = __fsub_rn(py, radius);

        for (int ty = ty0; ty <= ty1; ++ty) {
            const float Tf = (float)(ty * TILE_LEN);
            if ((yp > Tf) && (ym < Tf + (float)TILE_LEN)) {
                const int p = atomicAdd(&lpos[ty], 1);  // LDS atomic only
                bins_seg[(ty * nblk + blk) * SEGCAP + p] = i;
            }
        }
    }
    __syncthreads();

    // per-(block,row) counts: plain stores, fully overwritten every launch
    if (t < TYN) blkcnt[blk * TYN + t] = lpos[t];
}

// ---------------------------------------------------------------------------
// Kernel 2: per-row gather + stable depth sort (rank sort over unique
// 64-bit keys (depth_bits << 32) | idx; depth >= 0 so float bits are
// order-isomorphic). One 1024-thread block per tile-row.
// Emits dense sorted index list + row count.
// ---------------------------------------------------------------------------
__global__ __launch_bounds__(1024) void sort_rows(
    const float* __restrict__ depth, const int* __restrict__ blkcnt,
    const int* __restrict__ bins_seg, int* __restrict__ bins,
    int* __restrict__ rowcount, int nblk)
{
    __shared__ uint64_t keys[ROWCAP];          // 32 KiB
    __shared__ int segbase[NBLKMAX + 1];

    const int row = blockIdx.x;
    const int t = threadIdx.x;

    if (t == 0) {
        int s = 0;
        for (int b = 0; b < nblk; ++b) {
            segbase[b] = s;
            s += blkcnt[b * TYN + row];
        }
        segbase[nblk] = s;
        rowcount[row] = min(s, ROWCAP);
    }
    __syncthreads();

    const int C = min(segbase[nblk], ROWCAP);

    // gather all segments into dense LDS key array
    for (int b = 0; b < nblk; ++b) {
        const int base = segbase[b];
        const int cnt = segbase[b + 1] - base;
        for (int k = t; k < cnt; k += 1024) {
            const int dst = base + k;
            if (dst < ROWCAP) {
                const int idx = bins_seg[(row * nblk + b) * SEGCAP + k];
                keys[dst] = ((uint64_t)__float_as_uint(depth[idx]) << 32) | (uint32_t)idx;
            }
        }
    }
    __syncthreads();

    // rank sort: unique keys -> unique ranks -> direct scatter
    int* bl = bins + row * ROWCAP;
    for (int k = t; k < C; k += 1024) {
        const uint64_t mykey = keys[k];
        int rank = 0;
#pragma unroll 8
        for (int j = 0; j < C; ++j)
            rank += (keys[j] < mykey) ? 1 : 0;
        bl[rank] = (int)(uint32_t)mykey;
    }
}

// ---------------------------------------------------------------------------
// Kernel 3: per-tile render. One block per tile, 256 threads = 256 pixels.
// Phase 1: scan this tile-row's depth-sorted bin in chunks of 256,
//          ballot-compact first KMAX x-overlapping gaussians.
// Phase 2: fetch their params to LDS, per-pixel front-to-back blend.
// ---------------------------------------------------------------------------
__global__ __launch_bounds__(256) void render_tiles(
    const float4* __restrict__ pA0, const float4* __restrict__ pB0,
    const float4* __restrict__ pC0, const int* __restrict__ rowcount,
    const int* __restrict__ bins, float* __restrict__ out)
{
    __shared__ int    s_list[KMAX];
    __shared__ int    s_wcnt[4];
    __shared__ float4 pA[KMAX], pB[KMAX], pC[KMAX];

    const int tile = blockIdx.x;
    const int tx = tile / TYN;
    const int ty = tile % TYN;
    const float Lf = (float)(tx * TILE_LEN);
    const int t = threadIdx.x;
    const int lane = t & 63;
    const int w = t >> 6;

    const int C = min(rowcount[ty], ROWCAP);
    const int* bl = bins + ty * ROWCAP;

    // ---- Phase 1: ordered compaction of first KMAX x-overlapping gaussians
    int count = 0;  // block-uniform
    for (int base = 0; base < C; base += 256) {
        int g = -1;
        bool ov = false;
        if (base + t < C) {
            g = bl[base + t];
            const float4 A = pA0[g];
            ov = (__fadd_rn(A.x, A.z) > Lf) &&
                 (__fsub_rn(A.x, A.z) < Lf + (float)TILE_LEN);
        }
        const unsigned long long m = __ballot(ov);
        if (lane == 0) s_wcnt[w] = __popcll(m);
        __syncthreads();
        const int c0 = s_wcnt[0], c1 = s_wcnt[1], c2 = s_wcnt[2], c3 = s_wcnt[3];
        int off = count;
        if (w > 0) off += c0;
        if (w > 1) off += c1;
        if (w > 2) off += c2;
        const int pos = off + __popcll(m & ((1ull << lane) - 1ull));
        if (ov && pos < KMAX) s_list[pos] = g;
        count = min(KMAX, count + c0 + c1 + c2 + c3);
        __syncthreads();
        if (count >= KMAX) break;
    }

    // ---- fetch selected gaussian params into LDS
    if (t < count) {
        const int g = s_list[t];
        pA[t] = pA0[g];
        pB[t] = pB0[g];
        pC[t] = pC0[g];
    }
    __syncthreads();

    // ---- Phase 2: per-pixel blend (pixel (i,j): x = left+i, y = top+j)
    const int j = t & 15;
    const int i = t >> 4;
    const float x = Lf + (float)i;
    const float y = (float)(ty * TILE_LEN) + (float)j;

    float Tacc = 1.0f, cr = 0.0f, cg = 0.0f, cb = 0.0f;
    for (int k = 0; k < count; ++k) {
        const float4 A = pA[k];
        const float4 B = pB[k];
        const float4 Cc = pC[k];
        const float dx = x - A.x;
        const float dy = y - A.y;
        const float quad = (B.z * dx * dx - 2.0f * B.y * dx * dy + B.x * dy * dy) / B.w;
        const float prob = expf(-0.5f * quad);
        const float alpha = fminf(fmaxf(A.w * prob, 0.01f), 0.99f);
        const float wgt = alpha * Tacc;
        cr = fmaf(wgt, Cc.x, cr);
        cg = fmaf(wgt, Cc.y, cg);
        cb = fmaf(wgt, Cc.z, cb);
        Tacc *= (1.0f - alpha);
    }

    const int X = tx * TILE_LEN + i;
    const int Y = ty * TILE_LEN + j;
    float* o = out + ((size_t)X * IMGW + (size_t)Y) * 3;
    o[0] = cr;
    o[1] = cg;
    o[2] = cb;
}

// ---------------------------------------------------------------------------
extern "C" void kernel_launch(void* const* d_in, const int* in_sizes, int n_in,
                              void* d_out, int out_size, void* d_ws, size_t ws_size,
                              hipStream_t stream)
{
    const float* pos2d = (const float*)d_in[0];
    const float* cov2d = (const float*)d_in[1];
    const float* opac  = (const float*)d_in[2];
    const float* color = (const float*)d_in[3];
    const float* depth = (const float*)d_in[4];
    float* out = (float*)d_out;

    const int N = in_sizes[2];  // opacity count == N_GAUSS
    const int nblk = (N + PREPB - 1) / PREPB;   // 16 for N=16384

    // workspace layout (all fully overwritten each launch; no zeroing needed):
    //   pA/pB/pC: float4[N] each
    //   blkcnt:   int[nblk*TYN]
    //   rowcount: int[TYN]
    //   bins:     int[TYN*ROWCAP]        (dense sorted)
    //   bins_seg: int[TYN*nblk*SEGCAP]   (segmented unsorted)
    float4* pA = (float4*)d_ws;
    float4* pB = pA + N;
    float4* pC = pB + N;
    int* blkcnt   = (int*)(pC + N);
    int* rowcount = blkcnt + NBLKMAX * TYN;
    int* bins     = rowcount + 64;
    int* bins_seg = bins + TYN * ROWCAP;

    prep<<<nblk, PREPB, 0, stream>>>(
        pos2d, cov2d, opac, color, pA, pB, pC, blkcnt, bins_seg, nblk, N);

    sort_rows<<<TYN, 1024, 0, stream>>>(depth, blkcnt, bins_seg, bins, rowcount, nblk);

    render_tiles<<<TXN * TYN, 256, 0, stream>>>(pA, pB, pC, rowcount, bins, out);
}

// Round 5
// 36.974 us; speedup vs baseline: 1.6563x; 1.6563x over previous
//
#include <hip/hip_runtime.h>
#include <stdint.h>

#define TILE_LEN 16
#define KMAX 64
#define IMGW 512
#define IMGH 512
#define TXN 32
#define TYN 32
#define TPB 4                    // tiles per block (along x, same tile-row)
#define NBLK ((TXN * TYN) / TPB) // 256 blocks
#define BT 1024                  // threads per block
#define CCAP 256                 // per-tile candidate cap (mean ~46, ~30 sigma margin)

// ---------------------------------------------------------------------------
// Single fused kernel. Block b owns tiles (txb..txb+3, ty), ty = b & 31,
// txb = (b >> 5) * 4. Pipeline, all in LDS:
//   1) scan all N gaussians: radius (_rn chain, selection-exact), shared
//      y-overlap test, 4 x-overlap tests; append hits per tile via LDS
//      atomics (append order nondeterministic -- fixed by the sort).
//   2) per-tile stable depth sort: rank sort over unique 64-bit keys
//      (depth_bits << 32) | idx (depth >= 0 -> bits order-isomorphic).
//      Unique keys -> deterministic result regardless of append order.
//   3) gather first min(M,64) gaussians' params, front-to-back blend,
//      store. No workspace, no global intermediates, graph-replay safe.
// ---------------------------------------------------------------------------
__global__ __launch_bounds__(BT) void fused_splat(
    const float* __restrict__ pos2d, const float* __restrict__ cov2d,
    const float* __restrict__ opac,  const float* __restrict__ color,
    const float* __restrict__ depth, float* __restrict__ out, int N)
{
    __shared__ int      s_cnt[TPB];
    __shared__ int      s_cand[TPB][CCAP];
    __shared__ uint64_t s_keys[TPB][CCAP];
    __shared__ int      s_sel[TPB][KMAX];
    __shared__ float4   pA[TPB][KMAX], pB[TPB][KMAX], pC[TPB][KMAX];

    const int t   = threadIdx.x;
    const int ty  = blockIdx.x & (TYN - 1);
    const int txb = (blockIdx.x >> 5) * TPB;
    const float Tf  = (float)(ty * TILE_LEN);
    const float Lf0 = (float)(txb * TILE_LEN);

    if (t < TPB) s_cnt[t] = 0;
    __syncthreads();

    // ---- Phase 1: scan all gaussians, append per-tile candidates
    for (int base = 0; base < N; base += BT) {
        const int i = base + t;
        if (i < N) {
            const float2 p  = ((const float2*)pos2d)[i];
            const float4 cv = ((const float4*)cov2d)[i];   // [a, b, b, c]
            const float a = cv.x, b = cv.y, c = cv.w;

            // radius chain with _rn intrinsics: forbids fma contraction
            // (selection-critical, feeds exact bbox-overlap compares)
            const float trace = __fadd_rn(a, c);
            const float det   = __fsub_rn(__fmul_rn(a, c), __fmul_rn(b, b));
            float arg = __fsub_rn(__fmul_rn(trace, trace), __fmul_rn(4.0f, det));
            arg = fmaxf(arg, 0.0f);
            const float t1 = __fmul_rn(0.5f, trace);
            const float t2 = __fmul_rn(0.5f, sqrtf(arg));
            const float lam = fmaxf(__fsub_rn(t1, t2), __fadd_rn(t1, t2));
            const float r = __fmul_rn(3.0f, sqrtf(lam));

            const float yp = __fadd_rn(p.y, r);
            const float ym = __fsub_rn(p.y, r);
            if ((yp > Tf) && (ym < Tf + (float)TILE_LEN)) {
                const float xp = __fadd_rn(p.x, r);
                const float xm = __fsub_rn(p.x, r);
#pragma unroll
                for (int g = 0; g < TPB; ++g) {
                    const float Lf = Lf0 + (float)(g * TILE_LEN);
                    if ((xp > Lf) && (xm < Lf + (float)TILE_LEN)) {
                        const int pos = atomicAdd(&s_cnt[g], 1);   // LDS atomic
                        if (pos < CCAP) s_cand[g][pos] = i;
                    }
                }
            }
        }
    }
    __syncthreads();

    // ---- Phase 2: per-tile stable depth sort (rank sort, unique keys)
    const int g8  = t >> 8;    // tile group 0..3 (256 threads each)
    const int m   = t & 255;
    const int M   = min(s_cnt[g8], CCAP);

    uint64_t mykey = 0;
    int myidx = -1;
    if (m < M) {
        myidx = s_cand[g8][m];
        mykey = ((uint64_t)__float_as_uint(depth[myidx]) << 32) | (uint32_t)myidx;
        s_keys[g8][m] = mykey;
    }
    __syncthreads();

    if (m < M) {
        int rank = 0;
        for (int j = 0; j < M; ++j)
            rank += (s_keys[g8][j] < mykey) ? 1 : 0;
        if (rank < KMAX) s_sel[g8][rank] = myidx;   // unique ranks
    }
    __syncthreads();

    // ---- Phase 3a: gather selected gaussians' params into LDS
    if (t < TPB * KMAX) {
        const int g = t >> 6, k = t & 63;
        const int K = min(min(s_cnt[g], CCAP), KMAX);
        if (k < K) {
            const int idx = s_sel[g][k];
            const float2 p  = ((const float2*)pos2d)[idx];
            const float4 cv = ((const float4*)cov2d)[idx];
            const float det = __fsub_rn(__fmul_rn(cv.x, cv.w), __fmul_rn(cv.y, cv.y));
            pA[g][k] = make_float4(p.x, p.y, 0.0f, opac[idx]);
            pB[g][k] = make_float4(cv.x, cv.y, cv.w, det);
            pC[g][k] = make_float4(color[3 * idx], color[3 * idx + 1],
                                   color[3 * idx + 2], 0.0f);
        }
    }
    __syncthreads();

    // ---- Phase 3b: per-pixel front-to-back blend (all 1024 threads)
    const int pix = t & 255;
    const int pi = pix >> 4;       // x offset in tile
    const int pj = pix & 15;       // y offset in tile
    const int K = min(M, KMAX);
    const float x = Lf0 + (float)(g8 * TILE_LEN + pi);
    const float y = Tf + (float)pj;

    float Tacc = 1.0f, cr = 0.0f, cg = 0.0f, cb = 0.0f;
    for (int k = 0; k < K; ++k) {
        const float4 A  = pA[g8][k];
        const float4 B  = pB[g8][k];
        const float4 Cc = pC[g8][k];
        const float dx = x - A.x;
        const float dy = y - A.y;
        const float quad = (B.z * dx * dx - 2.0f * B.y * dx * dy + B.x * dy * dy) / B.w;
        const float prob = expf(-0.5f * quad);
        const float alpha = fminf(fmaxf(A.w * prob, 0.01f), 0.99f);
        const float wgt = alpha * Tacc;
        cr = fmaf(wgt, Cc.x, cr);
        cg = fmaf(wgt, Cc.y, cg);
        cb = fmaf(wgt, Cc.z, cb);
        Tacc *= (1.0f - alpha);
    }

    const int X = (txb + g8) * TILE_LEN + pi;
    const int Y = ty * TILE_LEN + pj;
    float* o = out + ((size_t)X * IMGW + (size_t)Y) * 3;
    o[0] = cr;
    o[1] = cg;
    o[2] = cb;
}

// ---------------------------------------------------------------------------
extern "C" void kernel_launch(void* const* d_in, const int* in_sizes, int n_in,
                              void* d_out, int out_size, void* d_ws, size_t ws_size,
                              hipStream_t stream)
{
    const float* pos2d = (const float*)d_in[0];
    const float* cov2d = (const float*)d_in[1];
    const float* opac  = (const float*)d_in[2];
    const float* color = (const float*)d_in[3];
    const float* depth = (const float*)d_in[4];
    float* out = (float*)d_out;

    const int N = in_sizes[2];  // opacity count == N_GAUSS

    fused_splat<<<NBLK, BT, 0, stream>>>(pos2d, cov2d, opac, color, depth, out, N);
}

// Round 6
// 28.270 us; speedup vs baseline: 2.1663x; 1.3079x over previous
//
#include <hip/hip_runtime.h>
#include <stdint.h>

#define TILE_LEN 16
#define KMAX 64
#define IMGW 512
#define IMGH 512
#define TXN 32
#define TYN 32
#define TPB 4                    // tiles per block (along x, same tile-row)
#define NBLK ((TXN * TYN) / TPB) // 256 blocks
#define BT 1024                  // threads per block
#define CCAP 256                 // per-tile candidate cap (mean ~46)
#define SURVCAP 3072             // block survivor cap (mean ~400)

// ---------------------------------------------------------------------------
// Single fused kernel. Block b owns tiles (txb..txb+3, ty), ty = b & 31.
//  1a) conservative sqrt-free prefilter: for PSD cov, lam_max <= trace, so
//      r <= 3*sqrt(trace). Reject if band-distance^2 > 9.2*trace (2% slack
//      makes it strictly conservative vs any fma/rounding drift). Survivors
//      ballot-compacted into LDS (order nondeterministic -- fixed by sort).
//  1b) exact _rn radius chain + exact y/x overlap tests on survivors only
//      (dense, all lanes active). Byte-identical selection arithmetic.
//  2)  per-tile stable depth sort: rank sort over unique 64-bit keys
//      (depth_bits << 32) | idx  (depth >= 0 -> bits order-isomorphic).
//  3)  gather first min(M,64) params (precompute 1/det), blend, store.
// ---------------------------------------------------------------------------
__global__ __launch_bounds__(BT) void fused_splat(
    const float* __restrict__ pos2d, const float* __restrict__ cov2d,
    const float* __restrict__ opac,  const float* __restrict__ color,
    const float* __restrict__ depth, float* __restrict__ out, int N)
{
    __shared__ int      s_scnt;
    __shared__ int      s_surv[SURVCAP];
    __shared__ int      s_cnt[TPB];
    __shared__ int      s_cand[TPB][CCAP];
    __shared__ uint64_t s_keys[TPB][CCAP];
    __shared__ int      s_sel[TPB][KMAX];
    __shared__ float4   pA[TPB][KMAX], pB[TPB][KMAX], pC[TPB][KMAX];

    const int t    = threadIdx.x;
    const int lane = t & 63;
    const int ty   = blockIdx.x & (TYN - 1);
    const int txb  = (blockIdx.x >> 5) * TPB;
    const float Tf  = (float)(ty * TILE_LEN);
    const float Lf0 = (float)(txb * TILE_LEN);
    const float Yc  = Tf + 8.0f;     // row band center
    const float Xc  = Lf0 + 32.0f;   // 4-tile band center

    if (t == 0) s_scnt = 0;
    if (t < TPB) s_cnt[t] = 0;
    __syncthreads();

    // ---- Phase 1a: conservative band prefilter + ballot compaction
#pragma unroll 2
    for (int base = 0; base < N; base += BT) {
        const int i = base + t;
        bool sv = false;
        if (i < N) {
            const float2 p  = ((const float2*)pos2d)[i];
            const float4 cv = ((const float4*)cov2d)[i];   // [a, b, b, c]
            const float rb2 = 9.2f * (cv.x + cv.w);        // (3*sqrt(trace))^2 * slack
            const float sy = fabsf(p.y - Yc) - 8.0f;
            const float sx = fabsf(p.x - Xc) - 32.0f;
            const bool rejY = (sy > 0.0f) && (sy * sy > rb2);
            const bool rejX = (sx > 0.0f) && (sx * sx > rb2);
            sv = !(rejY || rejX);
        }
        const unsigned long long msk = __ballot(sv);
        int wbase = 0;
        if (lane == 0 && msk) wbase = atomicAdd(&s_scnt, __popcll(msk));
        wbase = __shfl(wbase, 0);
        if (sv) {
            const int pos = wbase + __popcll(msk & ((1ull << lane) - 1ull));
            if (pos < SURVCAP) s_surv[pos] = i;
        }
    }
    __syncthreads();
    const int S = min(s_scnt, SURVCAP);

    // ---- Phase 1b: exact selection tests on survivors (dense)
    for (int k = t; k < S; k += BT) {
        const int i = s_surv[k];
        const float2 p  = ((const float2*)pos2d)[i];
        const float4 cv = ((const float4*)cov2d)[i];
        const float a = cv.x, b = cv.y, c = cv.w;

        // radius chain with _rn intrinsics: forbids fma contraction
        // (selection-critical, feeds exact bbox-overlap compares)
        const float trace = __fadd_rn(a, c);
        const float det   = __fsub_rn(__fmul_rn(a, c), __fmul_rn(b, b));
        float arg = __fsub_rn(__fmul_rn(trace, trace), __fmul_rn(4.0f, det));
        arg = fmaxf(arg, 0.0f);
        const float t1 = __fmul_rn(0.5f, trace);
        const float t2 = __fmul_rn(0.5f, sqrtf(arg));
        const float lam = fmaxf(__fsub_rn(t1, t2), __fadd_rn(t1, t2));
        const float r = __fmul_rn(3.0f, sqrtf(lam));

        const float yp = __fadd_rn(p.y, r);
        const float ym = __fsub_rn(p.y, r);
        if ((yp > Tf) && (ym < Tf + (float)TILE_LEN)) {
            const float xp = __fadd_rn(p.x, r);
            const float xm = __fsub_rn(p.x, r);
#pragma unroll
            for (int g = 0; g < TPB; ++g) {
                const float Lf = Lf0 + (float)(g * TILE_LEN);
                if ((xp > Lf) && (xm < Lf + (float)TILE_LEN)) {
                    const int pos = atomicAdd(&s_cnt[g], 1);   // LDS atomic
                    if (pos < CCAP) s_cand[g][pos] = i;
                }
            }
        }
    }
    __syncthreads();

    // ---- Phase 2: per-tile stable depth sort (rank sort, unique keys)
    const int g8 = t >> 8;    // tile group 0..3 (256 threads each)
    const int m  = t & 255;
    const int M  = min(s_cnt[g8], CCAP);

    uint64_t mykey = 0;
    int myidx = -1;
    if (m < M) {
        myidx = s_cand[g8][m];
        mykey = ((uint64_t)__float_as_uint(depth[myidx]) << 32) | (uint32_t)myidx;
        s_keys[g8][m] = mykey;
    }
    __syncthreads();

    if (m < M) {
        int rank = 0;
        for (int j = 0; j < M; ++j)
            rank += (s_keys[g8][j] < mykey) ? 1 : 0;
        if (rank < KMAX) s_sel[g8][rank] = myidx;   // unique ranks
    }
    __syncthreads();

    // ---- Phase 3a: gather selected gaussians' params into LDS
    if (t < TPB * KMAX) {
        const int g = t >> 6, k = t & 63;
        const int K = min(min(s_cnt[g], CCAP), KMAX);
        if (k < K) {
            const int idx = s_sel[g][k];
            const float2 p  = ((const float2*)pos2d)[idx];
            const float4 cv = ((const float4*)cov2d)[idx];
            const float det = __fsub_rn(__fmul_rn(cv.x, cv.w), __fmul_rn(cv.y, cv.y));
            pA[g][k] = make_float4(p.x, p.y, 0.0f, opac[idx]);
            pB[g][k] = make_float4(cv.x, cv.y, cv.w, 1.0f / det);
            pC[g][k] = make_float4(color[3 * idx], color[3 * idx + 1],
                                   color[3 * idx + 2], 0.0f);
        }
    }
    __syncthreads();

    // ---- Phase 3b: per-pixel front-to-back blend (all 1024 threads)
    const int pix = t & 255;
    const int pi = pix >> 4;       // x offset in tile
    const int pj = pix & 15;       // y offset in tile
    const int K = min(M, KMAX);
    const float x = Lf0 + (float)(g8 * TILE_LEN + pi);
    const float y = Tf + (float)pj;

    float Tacc = 1.0f, cr = 0.0f, cg = 0.0f, cb = 0.0f;
    for (int k = 0; k < K; ++k) {
        const float4 A  = pA[g8][k];
        const float4 B  = pB[g8][k];
        const float4 Cc = pC[g8][k];
        const float dx = x - A.x;
        const float dy = y - A.y;
        const float quad = (B.z * dx * dx - 2.0f * B.y * dx * dy + B.x * dy * dy) * B.w;
        const float prob = __expf(-0.5f * quad);
        const float alpha = fminf(fmaxf(A.w * prob, 0.01f), 0.99f);
        const float wgt = alpha * Tacc;
        cr = fmaf(wgt, Cc.x, cr);
        cg = fmaf(wgt, Cc.y, cg);
        cb = fmaf(wgt, Cc.z, cb);
        Tacc *= (1.0f - alpha);
    }

    const int X = (txb + g8) * TILE_LEN + pi;
    const int Y = ty * TILE_LEN + pj;
    float* o = out + ((size_t)X * IMGW + (size_t)Y) * 3;
    o[0] = cr;
    o[1] = cg;
    o[2] = cb;
}

// ---------------------------------------------------------------------------
extern "C" void kernel_launch(void* const* d_in, const int* in_sizes, int n_in,
                              void* d_out, int out_size, void* d_ws, size_t ws_size,
                              hipStream_t stream)
{
    const float* pos2d = (const float*)d_in[0];
    const float* cov2d = (const float*)d_in[1];
    const float* opac  = (const float*)d_in[2];
    const float* color = (const float*)d_in[3];
    const float* depth = (const float*)d_in[4];
    float* out = (float*)d_out;

    const int N = in_sizes[2];  // opacity count == N_GAUSS

    fused_splat<<<NBLK, BT, 0, stream>>>(pos2d, cov2d, opac, color, depth, out, N);
}